// Round 9
// baseline (215.865 us; speedup 1.0000x reference)
//
#include <hip/hip_runtime.h>

// SNN classifier: T=500, B=256, 96 -> 64 -> 80, leaky (subtract reset).
// f32 BLAS-order arithmetic replicated exactly (single-accumulator
// k-ascending __fmaf_rn chains; fixed leaky op-sequence) -> outputs
// bitwise-identical to the passing round-2..8 kernels.
//
// Round-9: rounds 6-8 were L1-REQUEST-bound: per-lane "streams" with
// 384B/64KB lane strides are 64-line gathers (16B used per line); L1
// serves ~1 line-req/cyc -> 4x oversubscribed -> VALUBusy ~25% (K1) /
// 12% (K3) regardless of scalar-path tweaks. Fix: coalesced global->LDS
// staging (the block's x/spk tile is a CONTIGUOUS global region), padded
// LDS rows for conflict-free ds_read_b128, weights stay on the scalar
// path, and outputs transpose through LDS into fully-linear block stores.
// K2/K4 untouched (already L3-served, ~3.5us combined).

#define T_STEPS 500
#define BATCH   256
#define N_IN    96
#define N_HID   64
#define N_OUT   80
#define CH      50   // chunk size in K2/K4 (500 = 10*50)

// ---------------- K1: cur1 = x @ W1 + b1 ----------------
// grid 500*4, block 256 (4 waves). Block = (t, 64-b group); wave = o-quarter.
// LDS: x tile staged [64 rows=b][96+4 pad], then reused for out transpose.
__global__ __launch_bounds__(256) void k1_cur1(
    const float* __restrict__ x,   // (T,B,96)
    const float* __restrict__ W1,  // (96,64)
    const float* __restrict__ b1,  // (64)
    float* __restrict__ cur1)      // (T,B,64) region inside outs
{
    const int t    = blockIdx.x >> 2;
    const int bg   = blockIdx.x & 3;
    const int b0   = bg << 6;
    const int lane = threadIdx.x & 63;   // = local b
    const int w    = threadIdx.x >> 6;   // wave id = o-quarter
    const int o0   = w << 4;

    __shared__ float sm[64 * 100];       // 25.6 KB; also reused as [64][72] out

    // ---- stage: 64x96 contiguous global region -> LDS rows padded to 100
    {
        const float4* __restrict__ src =
            reinterpret_cast<const float4*>(x + ((size_t)t * BATCH + b0) * N_IN);
        for (int i = threadIdx.x; i < 1536; i += 256) {     // 6 iters
            const float4 v = src[i];                        // fully coalesced
            const int row = i / 24, g = i % 24;
            *reinterpret_cast<float4*>(&sm[row * 100 + g * 4]) = v;
        }
    }
    __syncthreads();

    // ---- compute: lane reads its own padded row; W1 slices wave-uniform
    float acc[16];
    #pragma unroll
    for (int o = 0; o < 16; ++o) acc[o] = 0.0f;

    #pragma unroll
    for (int kg = 0; kg < 24; ++kg) {                       // 4-k granules
        const float4 xv =
            *reinterpret_cast<const float4*>(&sm[lane * 100 + kg * 4]);
        #pragma unroll
        for (int jj = 0; jj < 4; ++jj) {
            const int k = kg * 4 + jj;
            const float xsc = (jj == 0) ? xv.x : (jj == 1) ? xv.y
                            : (jj == 2) ? xv.z : xv.w;
            const float4* __restrict__ wr =
                reinterpret_cast<const float4*>(W1 + (size_t)k * N_HID + o0);
            const float4 w0 = wr[0], w1 = wr[1], w2 = wr[2], w3 = wr[3];
            acc[0]  = __fmaf_rn(xsc, w0.x, acc[0]);
            acc[1]  = __fmaf_rn(xsc, w0.y, acc[1]);
            acc[2]  = __fmaf_rn(xsc, w0.z, acc[2]);
            acc[3]  = __fmaf_rn(xsc, w0.w, acc[3]);
            acc[4]  = __fmaf_rn(xsc, w1.x, acc[4]);
            acc[5]  = __fmaf_rn(xsc, w1.y, acc[5]);
            acc[6]  = __fmaf_rn(xsc, w1.z, acc[6]);
            acc[7]  = __fmaf_rn(xsc, w1.w, acc[7]);
            acc[8]  = __fmaf_rn(xsc, w2.x, acc[8]);
            acc[9]  = __fmaf_rn(xsc, w2.y, acc[9]);
            acc[10] = __fmaf_rn(xsc, w2.z, acc[10]);
            acc[11] = __fmaf_rn(xsc, w2.w, acc[11]);
            acc[12] = __fmaf_rn(xsc, w3.x, acc[12]);
            acc[13] = __fmaf_rn(xsc, w3.y, acc[13]);
            acc[14] = __fmaf_rn(xsc, w3.z, acc[14]);
            acc[15] = __fmaf_rn(xsc, w3.w, acc[15]);
        }
    }

    // ---- bias, transpose via LDS, linear block store
    __syncthreads();                                        // x reads done
    #pragma unroll
    for (int o4 = 0; o4 < 4; ++o4) {
        float4 v;
        v.x = __fadd_rn(acc[o4 * 4 + 0], b1[o0 + o4 * 4 + 0]);
        v.y = __fadd_rn(acc[o4 * 4 + 1], b1[o0 + o4 * 4 + 1]);
        v.z = __fadd_rn(acc[o4 * 4 + 2], b1[o0 + o4 * 4 + 2]);
        v.w = __fadd_rn(acc[o4 * 4 + 3], b1[o0 + o4 * 4 + 3]);
        *reinterpret_cast<float4*>(&sm[lane * 72 + o0 + o4 * 4]) = v;
    }
    __syncthreads();
    {
        float4* __restrict__ dst =
            reinterpret_cast<float4*>(cur1 + ((size_t)t * BATCH + b0) * N_HID);
        for (int i = threadIdx.x; i < 1024; i += 256) {     // 4 iters, linear
            const int row = i / 16, g = i % 16;
            dst[i] = *reinterpret_cast<const float4*>(&sm[row * 72 + g * 4]);
        }
    }
}

// ---------------- K2: layer-1 recurrence (in-place cur1 -> spk) ----------------
__global__ __launch_bounds__(64) void k2_rec1(float* cs)  // outs region
{
    const int b = blockIdx.x;
    const int h = threadIdx.x;
    const size_t str  = (size_t)BATCH * N_HID;
    const size_t base = (size_t)b * N_HID + h;

    float A[CH], Bv[CH];
    #pragma unroll
    for (int i = 0; i < CH; ++i) A[i] = cs[(size_t)i * str + base];

    float mem = 0.f, s = 0.f;
    for (int cp = 0; cp < 5; ++cp) {            // 10 chunks, processed in pairs
        const int c0 = 2 * cp;
        #pragma unroll
        for (int i = 0; i < CH; ++i)            // prefetch chunk c0+1
            Bv[i] = cs[(size_t)((c0 + 1) * CH + i) * str + base];
        #pragma unroll
        for (int i = 0; i < CH; ++i) {          // compute chunk c0 from A
            const float m = __fsub_rn(__fadd_rn(__fmul_rn(0.95f, mem), A[i]), s);
            mem = m; s = (m > 1.0f) ? 1.0f : 0.0f;
            cs[(size_t)(c0 * CH + i) * str + base] = s;
        }
        if (cp < 4) {
            #pragma unroll
            for (int i = 0; i < CH; ++i)        // prefetch chunk c0+2
                A[i] = cs[(size_t)((c0 + 2) * CH + i) * str + base];
        }
        #pragma unroll
        for (int i = 0; i < CH; ++i) {          // compute chunk c0+1 from Bv
            const float m = __fsub_rn(__fadd_rn(__fmul_rn(0.95f, mem), Bv[i]), s);
            mem = m; s = (m > 1.0f) ? 1.0f : 0.0f;
            cs[(size_t)((c0 + 1) * CH + i) * str + base] = s;
        }
    }
}

// ---------------- K3: cur2 = spk @ W2 + b2 ----------------
// grid 500*4, block 256 (4 waves). Block = (t, 64-b group); wave = 20-o slice.
// LDS: spk tile [64][64+8 pad], reused as [64][84] out.
__global__ __launch_bounds__(256) void k3_cur2(
    const float* __restrict__ spk,  // (T,B,64) in outs
    const float* __restrict__ W2,   // (64,80)
    const float* __restrict__ b2,   // (80)
    float* __restrict__ cur2)       // (T,B,80) = outm region
{
    const int t    = blockIdx.x >> 2;
    const int bg   = blockIdx.x & 3;
    const int b0   = bg << 6;
    const int lane = threadIdx.x & 63;   // = local b
    const int w    = threadIdx.x >> 6;   // wave id
    const int o0   = w * 20;

    __shared__ float sm[64 * 84];        // 21.5 KB (>= 64*72 stage view)

    // ---- stage: 64x64 contiguous global region -> LDS rows padded to 72
    {
        const float4* __restrict__ src =
            reinterpret_cast<const float4*>(spk + ((size_t)t * BATCH + b0) * N_HID);
        for (int i = threadIdx.x; i < 1024; i += 256) {     // 4 iters
            const float4 v = src[i];                        // fully coalesced
            const int row = i / 16, g = i % 16;
            *reinterpret_cast<float4*>(&sm[row * 72 + g * 4]) = v;
        }
    }
    __syncthreads();

    float acc[20];
    #pragma unroll
    for (int o = 0; o < 20; ++o) acc[o] = 0.0f;

    #pragma unroll
    for (int kg = 0; kg < 16; ++kg) {
        const float4 xv =
            *reinterpret_cast<const float4*>(&sm[lane * 72 + kg * 4]);
        #pragma unroll
        for (int jj = 0; jj < 4; ++jj) {
            const int k = kg * 4 + jj;
            const float sv = (jj == 0) ? xv.x : (jj == 1) ? xv.y
                           : (jj == 2) ? xv.z : xv.w;
            const float4* __restrict__ wr =
                reinterpret_cast<const float4*>(W2 + (size_t)k * N_OUT + o0);
            const float4 w0 = wr[0], w1 = wr[1], w2 = wr[2], w3 = wr[3], w4 = wr[4];
            acc[0]  = __fmaf_rn(sv, w0.x, acc[0]);
            acc[1]  = __fmaf_rn(sv, w0.y, acc[1]);
            acc[2]  = __fmaf_rn(sv, w0.z, acc[2]);
            acc[3]  = __fmaf_rn(sv, w0.w, acc[3]);
            acc[4]  = __fmaf_rn(sv, w1.x, acc[4]);
            acc[5]  = __fmaf_rn(sv, w1.y, acc[5]);
            acc[6]  = __fmaf_rn(sv, w1.z, acc[6]);
            acc[7]  = __fmaf_rn(sv, w1.w, acc[7]);
            acc[8]  = __fmaf_rn(sv, w2.x, acc[8]);
            acc[9]  = __fmaf_rn(sv, w2.y, acc[9]);
            acc[10] = __fmaf_rn(sv, w2.z, acc[10]);
            acc[11] = __fmaf_rn(sv, w2.w, acc[11]);
            acc[12] = __fmaf_rn(sv, w3.x, acc[12]);
            acc[13] = __fmaf_rn(sv, w3.y, acc[13]);
            acc[14] = __fmaf_rn(sv, w3.z, acc[14]);
            acc[15] = __fmaf_rn(sv, w3.w, acc[15]);
            acc[16] = __fmaf_rn(sv, w4.x, acc[16]);
            acc[17] = __fmaf_rn(sv, w4.y, acc[17]);
            acc[18] = __fmaf_rn(sv, w4.z, acc[18]);
            acc[19] = __fmaf_rn(sv, w4.w, acc[19]);
        }
    }

    __syncthreads();                                        // spk reads done
    #pragma unroll
    for (int o4 = 0; o4 < 5; ++o4) {
        float4 v;
        v.x = __fadd_rn(acc[o4 * 4 + 0], b2[o0 + o4 * 4 + 0]);
        v.y = __fadd_rn(acc[o4 * 4 + 1], b2[o0 + o4 * 4 + 1]);
        v.z = __fadd_rn(acc[o4 * 4 + 2], b2[o0 + o4 * 4 + 2]);
        v.w = __fadd_rn(acc[o4 * 4 + 3], b2[o0 + o4 * 4 + 3]);
        *reinterpret_cast<float4*>(&sm[lane * 84 + o0 + o4 * 4]) = v;
    }
    __syncthreads();
    {
        float4* __restrict__ dst =
            reinterpret_cast<float4*>(cur2 + ((size_t)t * BATCH + b0) * N_OUT);
        for (int i = threadIdx.x; i < 1280; i += 256) {     // 5 iters, linear
            const int row = i / 20, g = i % 20;
            dst[i] = *reinterpret_cast<const float4*>(&sm[row * 84 + g * 4]);
        }
    }
}

// ---------------- K4: layer-2 recurrence (cur2 in outm -> spk/mem finals) ----------------
__global__ __launch_bounds__(80) void k4_rec2(float* cm, float* os)
{
    const int b = blockIdx.x;
    const int o = threadIdx.x;   // 0..79
    const size_t str  = (size_t)BATCH * N_OUT;
    const size_t base = (size_t)b * N_OUT + o;

    float A[CH], Bv[CH];
    #pragma unroll
    for (int i = 0; i < CH; ++i) A[i] = cm[(size_t)i * str + base];

    float mem = 0.f, s = 0.f;
    for (int cp = 0; cp < 5; ++cp) {
        const int c0 = 2 * cp;
        #pragma unroll
        for (int i = 0; i < CH; ++i)
            Bv[i] = cm[(size_t)((c0 + 1) * CH + i) * str + base];
        #pragma unroll
        for (int i = 0; i < CH; ++i) {
            const int t = c0 * CH + i;
            const float m = __fsub_rn(__fadd_rn(__fmul_rn(0.95f, mem), A[i]), s);
            mem = m; s = (m > 1.0f) ? 1.0f : 0.0f;
            os[(size_t)t * str + base] = s;
            cm[(size_t)t * str + base] = m;
        }
        if (cp < 4) {
            #pragma unroll
            for (int i = 0; i < CH; ++i)
                A[i] = cm[(size_t)((c0 + 2) * CH + i) * str + base];
        }
        #pragma unroll
        for (int i = 0; i < CH; ++i) {
            const int t = (c0 + 1) * CH + i;
            const float m = __fsub_rn(__fadd_rn(__fmul_rn(0.95f, mem), Bv[i]), s);
            mem = m; s = (m > 1.0f) ? 1.0f : 0.0f;
            os[(size_t)t * str + base] = s;
            cm[(size_t)t * str + base] = m;
        }
    }
}

extern "C" void kernel_launch(void* const* d_in, const int* in_sizes, int n_in,
                              void* d_out, int out_size, void* d_ws, size_t ws_size,
                              hipStream_t stream) {
    const float* x  = (const float*)d_in[0];
    const float* W1 = (const float*)d_in[1];
    const float* b1 = (const float*)d_in[2];
    const float* W2 = (const float*)d_in[3];
    const float* b2 = (const float*)d_in[4];
    float* outs = (float*)d_out;                                   // (T,B,80) spikes
    float* outm = outs + (size_t)T_STEPS * BATCH * N_OUT;          // (T,B,80) mem

    k1_cur1<<<T_STEPS * 4, 256, 0, stream>>>(x, W1, b1, outs);     // cur1 -> outs
    k2_rec1<<<BATCH, 64, 0, stream>>>(outs);                       // spk overwrites cur1
    k3_cur2<<<T_STEPS * 4, 256, 0, stream>>>(outs, W2, b2, outm);  // cur2 -> outm
    k4_rec2<<<BATCH, 80, 0, stream>>>(outm, outs);                 // finals in place
}